// Round 1
// baseline (548.142 us; speedup 1.0000x reference)
//
#include <hip/hip_runtime.h>

#define NG 72
#define NB 64

// conv1: x (64,216,46,46) -> conv k5 g72 (3->8/group) -> relu -> pool2 -> (64,576,21,21)
__global__ __launch_bounds__(256) void conv1_k(const float* __restrict__ x,
                                               const float* __restrict__ w,
                                               const float* __restrict__ bias,
                                               float* __restrict__ out) {
  const int b = blockIdx.x / NG, g = blockIdx.x % NG;
  __shared__ float sx[3 * 46 * 46];   // 6348
  __shared__ float sw[8 * 75];        // 600
  __shared__ float sb[8];
  const float* xp = x + (size_t)(b * 216 + g * 3) * 2116;
  for (int i = threadIdx.x; i < 6348; i += 256) sx[i] = xp[i];
  const float* wp = w + (size_t)(g * 8) * 75;
  for (int i = threadIdx.x; i < 600; i += 256) sw[i] = wp[i];
  if (threadIdx.x < 8) sb[threadIdx.x] = bias[g * 8 + threadIdx.x];
  __syncthreads();
  for (int idx = threadIdx.x; idx < 8 * 441; idx += 256) {
    const int oc = idx / 441, p = idx % 441;
    const int py = p / 21, px = p % 21;
    const int iy = 2 * py, ix = 2 * px;
    float a00 = 0.f, a01 = 0.f, a10 = 0.f, a11 = 0.f;
#pragma unroll
    for (int ic = 0; ic < 3; ic++) {
      float win[6][6];
      const float* sp = sx + ic * 2116 + iy * 46 + ix;
#pragma unroll
      for (int r = 0; r < 6; r++)
#pragma unroll
        for (int c = 0; c < 6; c++) win[r][c] = sp[r * 46 + c];
      const float* wq = sw + oc * 75 + ic * 25;
#pragma unroll
      for (int ky = 0; ky < 5; ky++)
#pragma unroll
        for (int kx = 0; kx < 5; kx++) {
          const float wv = wq[ky * 5 + kx];
          a00 = fmaf(win[ky][kx],         wv, a00);
          a01 = fmaf(win[ky][kx + 1],     wv, a01);
          a10 = fmaf(win[ky + 1][kx],     wv, a10);
          a11 = fmaf(win[ky + 1][kx + 1], wv, a11);
        }
    }
    float v = fmaxf(fmaxf(a00, a01), fmaxf(a10, a11)) + sb[oc];
    out[(size_t)(b * 576 + g * 8 + oc) * 441 + p] = fmaxf(v, 0.f);
  }
}

// conv2: (64,576,21,21) -> conv k3 (8->16/group) -> relu -> pool2 -> (64,1152,9,9)
__global__ __launch_bounds__(256) void conv2_k(const float* __restrict__ x,
                                               const float* __restrict__ w,
                                               const float* __restrict__ bias,
                                               float* __restrict__ out) {
  const int b = blockIdx.x / NG, g = blockIdx.x % NG;
  __shared__ float sx[8 * 441];   // 3528
  __shared__ float sw[16 * 72];   // 1152
  __shared__ float sb[16];
  const float* xp = x + (size_t)(b * 576 + g * 8) * 441;
  for (int i = threadIdx.x; i < 8 * 441; i += 256) sx[i] = xp[i];
  const float* wp = w + (size_t)(g * 16) * 72;
  for (int i = threadIdx.x; i < 16 * 72; i += 256) sw[i] = wp[i];
  if (threadIdx.x < 16) sb[threadIdx.x] = bias[g * 16 + threadIdx.x];
  __syncthreads();
  for (int idx = threadIdx.x; idx < 16 * 81; idx += 256) {
    const int oc = idx / 81, p = idx % 81;
    const int py = p / 9, px = p % 9;
    const int iy = 2 * py, ix = 2 * px;
    float a00 = 0.f, a01 = 0.f, a10 = 0.f, a11 = 0.f;
#pragma unroll
    for (int ic = 0; ic < 8; ic++) {
      float win[4][4];
      const float* sp = sx + ic * 441 + iy * 21 + ix;
#pragma unroll
      for (int r = 0; r < 4; r++)
#pragma unroll
        for (int c = 0; c < 4; c++) win[r][c] = sp[r * 21 + c];
      const float* wq = sw + oc * 72 + ic * 9;
#pragma unroll
      for (int ky = 0; ky < 3; ky++)
#pragma unroll
        for (int kx = 0; kx < 3; kx++) {
          const float wv = wq[ky * 3 + kx];
          a00 = fmaf(win[ky][kx],         wv, a00);
          a01 = fmaf(win[ky][kx + 1],     wv, a01);
          a10 = fmaf(win[ky + 1][kx],     wv, a10);
          a11 = fmaf(win[ky + 1][kx + 1], wv, a11);
        }
    }
    float v = fmaxf(fmaxf(a00, a01), fmaxf(a10, a11)) + sb[oc];
    out[(size_t)(b * 1152 + g * 16 + oc) * 81 + p] = fmaxf(v, 0.f);
  }
}

// conv3: (64,1152,9,9) -> conv k3 (16->32/group) -> relu -> pool2 -> (64,2304,3,3)
__global__ __launch_bounds__(256) void conv3_k(const float* __restrict__ x,
                                               const float* __restrict__ w,
                                               const float* __restrict__ bias,
                                               float* __restrict__ out) {
  const int b = blockIdx.x / NG, g = blockIdx.x % NG;
  __shared__ float sx[16 * 81];    // 1296
  __shared__ float sw[32 * 144];   // 4608
  __shared__ float sb[32];
  const float* xp = x + (size_t)(b * 1152 + g * 16) * 81;
  for (int i = threadIdx.x; i < 16 * 81; i += 256) sx[i] = xp[i];
  const float* wp = w + (size_t)(g * 32) * 144;
  for (int i = threadIdx.x; i < 32 * 144; i += 256) sw[i] = wp[i];
  if (threadIdx.x < 32) sb[threadIdx.x] = bias[g * 32 + threadIdx.x];
  __syncthreads();
  for (int idx = threadIdx.x; idx < 32 * 9; idx += 256) {
    const int oc = idx / 9, p = idx % 9;
    const int py = p / 3, px = p % 3;
    const int iy = 2 * py, ix = 2 * px;
    float a00 = 0.f, a01 = 0.f, a10 = 0.f, a11 = 0.f;
#pragma unroll
    for (int ic = 0; ic < 16; ic++) {
      float win[4][4];
      const float* sp = sx + ic * 81 + iy * 9 + ix;
#pragma unroll
      for (int r = 0; r < 4; r++)
#pragma unroll
        for (int c = 0; c < 4; c++) win[r][c] = sp[r * 9 + c];
      const float* wq = sw + oc * 144 + ic * 9;
#pragma unroll
      for (int ky = 0; ky < 3; ky++)
#pragma unroll
        for (int kx = 0; kx < 3; kx++) {
          const float wv = wq[ky * 3 + kx];
          a00 = fmaf(win[ky][kx],         wv, a00);
          a01 = fmaf(win[ky][kx + 1],     wv, a01);
          a10 = fmaf(win[ky + 1][kx],     wv, a10);
          a11 = fmaf(win[ky + 1][kx + 1], wv, a11);
        }
    }
    float v = fmaxf(fmaxf(a00, a01), fmaxf(a10, a11)) + sb[oc];
    out[(size_t)(b * 2304 + g * 32 + oc) * 9 + p] = fmaxf(v, 0.f);
  }
}

// fused block-diagonal linear1 (288->64 per group) + linear2 (64->2 per group) + bias
// one block per group; h is (64, 20736) with group g occupying cols [g*288, (g+1)*288)
__global__ __launch_bounds__(256) void lin_k(const float* __restrict__ h,
                                             const float* __restrict__ w1,
                                             const float* __restrict__ w2,
                                             const float* __restrict__ b2,
                                             float* __restrict__ out) {
  const int g = blockIdx.x;
  __shared__ float sw1[64 * 289];  // padded: 288 % 32 == 0 would be 32-way bank conflict
  __shared__ float so[64 * 65];    // out1 for all 64 batches, padded
  __shared__ float sw2[2 * 64];
  __shared__ float sb2[2];
  for (int i = threadIdx.x; i < 64 * 288; i += 256) {
    const int o = i / 288, k = i % 288;
    sw1[o * 289 + k] = w1[(size_t)(g * 64 + o) * 20736 + g * 288 + k];
  }
  if (threadIdx.x < 128) {
    const int j = threadIdx.x / 64, o = threadIdx.x % 64;
    sw2[j * 64 + o] = w2[(size_t)(g * 2 + j) * 4608 + g * 64 + o];
  }
  if (threadIdx.x < 2) sb2[threadIdx.x] = b2[g * 2 + threadIdx.x];
  __syncthreads();
  for (int idx = threadIdx.x; idx < 64 * 64; idx += 256) {
    const int bb = idx / 64, o = idx % 64;
    const float* f = h + (size_t)bb * 20736 + g * 288;
    float acc = 0.f;
#pragma unroll 4
    for (int k = 0; k < 288; k++) acc = fmaf(f[k], sw1[o * 289 + k], acc);
    so[bb * 65 + o] = acc;
  }
  __syncthreads();
  if (threadIdx.x < 128) {
    const int bb = threadIdx.x / 2, j = threadIdx.x % 2;
    float acc = sb2[j];
#pragma unroll
    for (int o = 0; o < 64; o++) acc = fmaf(so[bb * 65 + o], sw2[j * 64 + o], acc);
    out[bb * 144 + g * 2 + j] = acc;
  }
}

extern "C" void kernel_launch(void* const* d_in, const int* in_sizes, int n_in,
                              void* d_out, int out_size, void* d_ws, size_t ws_size,
                              hipStream_t stream) {
  const float* x   = (const float*)d_in[0];
  const float* w1  = (const float*)d_in[1];
  const float* b1  = (const float*)d_in[2];
  const float* w2  = (const float*)d_in[3];
  const float* b2  = (const float*)d_in[4];
  const float* w3  = (const float*)d_in[5];
  const float* b3  = (const float*)d_in[6];
  const float* l1w = (const float*)d_in[7];
  const float* l2w = (const float*)d_in[8];
  const float* l2b = (const float*)d_in[9];
  float* out = (float*)d_out;

  float* h1 = (float*)d_ws;          // 64*576*21*21  = 16,257,024 floats
  float* h2 = h1 + 16257024;         // 64*1152*9*9   =  5,971,968 floats
  float* h3 = h2 + 5971968;          // 64*2304*3*3   =  1,327,104 floats (total ~94.2 MB)

  conv1_k<<<dim3(NB * NG), 256, 0, stream>>>(x,  w1, b1, h1);
  conv2_k<<<dim3(NB * NG), 256, 0, stream>>>(h1, w2, b2, h2);
  conv3_k<<<dim3(NB * NG), 256, 0, stream>>>(h2, w3, b3, h3);
  lin_k  <<<dim3(NG),      256, 0, stream>>>(h3, l1w, l2w, l2b, out);
}

// Round 2
// 470.687 us; speedup vs baseline: 1.1646x; 1.1646x over previous
//
#include <hip/hip_runtime.h>

#define NG 72

// WIN(E,O,r,c): window element at row r, col c where E/O are de-interleaved
// even/odd column register arrays (c is compile-time after unroll)
#define WIN(E, O, r, c) (((c) & 1) ? (O)[(r)][(c) >> 1] : (E)[(r)][(c) >> 1])

// ---------------- conv1: (64,216,46,46) -> k5 g72 (3->8) -> relu -> pool2 -> (64,576,21,21)
__global__ __launch_bounds__(256) void conv1_k(const float* __restrict__ x,
                                               const float* __restrict__ w,
                                               const float* __restrict__ bias,
                                               float* __restrict__ out) {
  const int b = blockIdx.x / NG, g = blockIdx.x % NG;
  __shared__ float sxe[3][46][25];   // even cols (23 used), odd pitch kills conflicts
  __shared__ float sxo[3][46][25];   // odd cols (23 used)
  __shared__ float sw[8 * 3 * 28];   // per-(oc,ic) padded 25->28 for aligned float4
  __shared__ float sb[8];
  const float* xp = x + (size_t)(b * 216 + g * 3) * 2116;
  for (int i = threadIdx.x; i < 3 * 2116; i += 256) {
    const int ic = i / 2116, rem = i % 2116, r = rem / 46, c = rem % 46;
    const float v = xp[i];
    if (c & 1) sxo[ic][r][c >> 1] = v; else sxe[ic][r][c >> 1] = v;
  }
  const float* wp = w + (size_t)(g * 8) * 75;
  for (int i = threadIdx.x; i < 600; i += 256) {
    const int oc = i / 75, rem = i % 75, ic = rem / 25, k = rem % 25;
    sw[(oc * 3 + ic) * 28 + k] = wp[i];
  }
  if (threadIdx.x < 8) sb[threadIdx.x] = bias[g * 8 + threadIdx.x];
  __syncthreads();
  for (int p = threadIdx.x; p < 441; p += 256) {
    const int py = p / 21, px = p % 21, iy = 2 * py;
    float acc[8][4];
#pragma unroll
    for (int o = 0; o < 8; o++)
#pragma unroll
      for (int q = 0; q < 4; q++) acc[o][q] = 0.f;
#pragma unroll
    for (int ic = 0; ic < 3; ic++) {
      float we[6][3], wo[6][3];
#pragma unroll
      for (int r = 0; r < 6; r++)
#pragma unroll
        for (int j = 0; j < 3; j++) {
          we[r][j] = sxe[ic][iy + r][px + j];
          wo[r][j] = sxo[ic][iy + r][px + j];
        }
#pragma unroll
      for (int oc = 0; oc < 8; oc++) {
        float wv[28];
        const float4* wq = (const float4*)&sw[(oc * 3 + ic) * 28];
#pragma unroll
        for (int q = 0; q < 7; q++) ((float4*)wv)[q] = wq[q];
#pragma unroll
        for (int ky = 0; ky < 5; ky++)
#pragma unroll
          for (int kx = 0; kx < 5; kx++) {
            const float wv_ = wv[ky * 5 + kx];
            acc[oc][0] = fmaf(WIN(we, wo, ky,     kx),     wv_, acc[oc][0]);
            acc[oc][1] = fmaf(WIN(we, wo, ky,     kx + 1), wv_, acc[oc][1]);
            acc[oc][2] = fmaf(WIN(we, wo, ky + 1, kx),     wv_, acc[oc][2]);
            acc[oc][3] = fmaf(WIN(we, wo, ky + 1, kx + 1), wv_, acc[oc][3]);
          }
      }
    }
#pragma unroll
    for (int oc = 0; oc < 8; oc++) {
      const float v = fmaxf(fmaxf(acc[oc][0], acc[oc][1]), fmaxf(acc[oc][2], acc[oc][3])) + sb[oc];
      out[(size_t)(b * 576 + g * 8 + oc) * 441 + p] = fmaxf(v, 0.f);
    }
  }
}

// ---------------- conv2: (64,576,21,21) -> k3 (8->16) -> relu -> pool2 -> (64,1152,9,9)
#define C2_NBB 3
__global__ __launch_bounds__(256) void conv2_k(const float* __restrict__ x,
                                               const float* __restrict__ w,
                                               const float* __restrict__ bias,
                                               float* __restrict__ out) {
  const int g = blockIdx.x % NG, b0 = (blockIdx.x / NG) * C2_NBB;
  const int nbb = min(C2_NBB, 64 - b0);
  __shared__ float sxe[C2_NBB][8][21][12];  // even cols (11 used)
  __shared__ float sxo[C2_NBB][8][21][12];  // odd cols (10 used)
  __shared__ float sw[16 * 8 * 12];         // per-(oc,ic) padded 9->12
  __shared__ float sb[16];
  for (int bb = 0; bb < nbb; bb++) {
    const float* xp = x + (size_t)((b0 + bb) * 576 + g * 8) * 441;
    for (int i = threadIdx.x; i < 8 * 441; i += 256) {
      const int ic = i / 441, rem = i % 441, r = rem / 21, c = rem % 21;
      const float v = xp[i];
      if (c & 1) sxo[bb][ic][r][c >> 1] = v; else sxe[bb][ic][r][c >> 1] = v;
    }
  }
  const float* wp = w + (size_t)(g * 16) * 72;
  for (int i = threadIdx.x; i < 16 * 72; i += 256) {
    const int oc = i / 72, rem = i % 72, ic = rem / 9, k = rem % 9;
    sw[(oc * 8 + ic) * 12 + k] = wp[i];
  }
  if (threadIdx.x < 16) sb[threadIdx.x] = bias[g * 16 + threadIdx.x];
  __syncthreads();
  for (int u = threadIdx.x; u < nbb * 81; u += 256) {
    const int bb = u / 81, p = u % 81, py = p / 9, px = p % 9, iy = 2 * py;
    float acc[16][4];
#pragma unroll
    for (int o = 0; o < 16; o++)
#pragma unroll
      for (int q = 0; q < 4; q++) acc[o][q] = 0.f;
#pragma unroll
    for (int ic = 0; ic < 8; ic++) {
      float we[4][2], wo[4][2];
#pragma unroll
      for (int r = 0; r < 4; r++)
#pragma unroll
        for (int j = 0; j < 2; j++) {
          we[r][j] = sxe[bb][ic][iy + r][px + j];
          wo[r][j] = sxo[bb][ic][iy + r][px + j];
        }
#pragma unroll
      for (int oc = 0; oc < 16; oc++) {
        float wv[12];
        const float4* wq = (const float4*)&sw[(oc * 8 + ic) * 12];
#pragma unroll
        for (int q = 0; q < 3; q++) ((float4*)wv)[q] = wq[q];
#pragma unroll
        for (int ky = 0; ky < 3; ky++)
#pragma unroll
          for (int kx = 0; kx < 3; kx++) {
            const float wv_ = wv[ky * 3 + kx];
            acc[oc][0] = fmaf(WIN(we, wo, ky,     kx),     wv_, acc[oc][0]);
            acc[oc][1] = fmaf(WIN(we, wo, ky,     kx + 1), wv_, acc[oc][1]);
            acc[oc][2] = fmaf(WIN(we, wo, ky + 1, kx),     wv_, acc[oc][2]);
            acc[oc][3] = fmaf(WIN(we, wo, ky + 1, kx + 1), wv_, acc[oc][3]);
          }
      }
    }
#pragma unroll
    for (int oc = 0; oc < 16; oc++) {
      const float v = fmaxf(fmaxf(acc[oc][0], acc[oc][1]), fmaxf(acc[oc][2], acc[oc][3])) + sb[oc];
      out[(size_t)((b0 + bb) * 1152 + g * 16 + oc) * 81 + p] = fmaxf(v, 0.f);
    }
  }
}

// ---------------- conv3: (64,1152,9,9) -> k3 (16->32) -> relu -> pool2 -> (64,2304,3,3)
#define C3_NBB 7
__global__ __launch_bounds__(256) void conv3_k(const float* __restrict__ x,
                                               const float* __restrict__ w,
                                               const float* __restrict__ bias,
                                               float* __restrict__ out) {
  const int g = blockIdx.x % NG, b0 = (blockIdx.x / NG) * C3_NBB;
  const int nbb = min(C3_NBB, 64 - b0);
  __shared__ float sx[C3_NBB][16][81];
  __shared__ float sw[32 * 16 * 12];
  __shared__ float sb[32];
  for (int bb = 0; bb < nbb; bb++) {
    const float* xp = x + (size_t)((b0 + bb) * 1152 + g * 16) * 81;
    for (int i = threadIdx.x; i < 16 * 81; i += 256) sx[bb][i / 81][i % 81] = xp[i];
  }
  const float* wp = w + (size_t)(g * 32) * 144;
  for (int i = threadIdx.x; i < 32 * 144; i += 256) {
    const int oc = i / 144, rem = i % 144, ic = rem / 9, k = rem % 9;
    sw[(oc * 16 + ic) * 12 + k] = wp[i];
  }
  if (threadIdx.x < 32) sb[threadIdx.x] = bias[g * 32 + threadIdx.x];
  __syncthreads();
  for (int u = threadIdx.x; u < nbb * 36; u += 256) {
    const int bb = u / 36, rem = u % 36, ocg = rem / 9, p = rem % 9;
    const int py = p / 3, px = p % 3, iy = 2 * py, ix = 2 * px;
    float acc[8][4];
#pragma unroll
    for (int o = 0; o < 8; o++)
#pragma unroll
      for (int q = 0; q < 4; q++) acc[o][q] = 0.f;
#pragma unroll
    for (int ic = 0; ic < 16; ic++) {
      float win[4][4];
#pragma unroll
      for (int r = 0; r < 4; r++)
#pragma unroll
        for (int c = 0; c < 4; c++) win[r][c] = sx[bb][ic][(iy + r) * 9 + ix + c];
#pragma unroll
      for (int o8 = 0; o8 < 8; o8++) {
        const int oc = ocg * 8 + o8;
        float wv[12];
        const float4* wq = (const float4*)&sw[(oc * 16 + ic) * 12];
#pragma unroll
        for (int q = 0; q < 3; q++) ((float4*)wv)[q] = wq[q];
#pragma unroll
        for (int ky = 0; ky < 3; ky++)
#pragma unroll
          for (int kx = 0; kx < 3; kx++) {
            const float wv_ = wv[ky * 3 + kx];
            acc[o8][0] = fmaf(win[ky][kx],         wv_, acc[o8][0]);
            acc[o8][1] = fmaf(win[ky][kx + 1],     wv_, acc[o8][1]);
            acc[o8][2] = fmaf(win[ky + 1][kx],     wv_, acc[o8][2]);
            acc[o8][3] = fmaf(win[ky + 1][kx + 1], wv_, acc[o8][3]);
          }
      }
    }
#pragma unroll
    for (int o8 = 0; o8 < 8; o8++) {
      const int oc = ocg * 8 + o8;
      const float v = fmaxf(fmaxf(acc[o8][0], acc[o8][1]), fmaxf(acc[o8][2], acc[o8][3])) + sb[oc];
      out[(size_t)((b0 + bb) * 2304 + g * 32 + oc) * 9 + p] = fmaxf(v, 0.f);
    }
  }
}

// ---------------- fused block-diagonal linear1 (288->64) + linear2 (64->2) + bias
// grid = 2 x 72: each block handles 32 batches of one group.
__global__ __launch_bounds__(256) void lin_k(const float* __restrict__ h,
                                             const float* __restrict__ w1,
                                             const float* __restrict__ w2,
                                             const float* __restrict__ b2,
                                             float* __restrict__ out) {
  const int g = blockIdx.x % NG, b0 = (blockIdx.x / NG) * 32;
  __shared__ float sw1[64 * 292];  // rows padded to 292 (=4*73): b128 reads conflict-free
  __shared__ float sf[32 * 300];   // rows padded to 300: lane-stride 300%32=12 -> 2-way max
  __shared__ float so[32 * 65];
  __shared__ float sw2[2 * 64];
  __shared__ float sb2[2];
  for (int i = threadIdx.x; i < 64 * 288; i += 256) {
    const int o = i / 288, k = i % 288;
    sw1[o * 292 + k] = w1[(size_t)(g * 64 + o) * 20736 + g * 288 + k];
  }
  for (int i = threadIdx.x; i < 32 * 288; i += 256) {
    const int bb = i / 288, k = i % 288;
    sf[bb * 300 + k] = h[(size_t)(b0 + bb) * 20736 + g * 288 + k];
  }
  if (threadIdx.x < 128) {
    const int j = threadIdx.x >> 6, o = threadIdx.x & 63;
    sw2[j * 64 + o] = w2[(size_t)(g * 2 + j) * 4608 + g * 64 + o];
  }
  if (threadIdx.x < 2) sb2[threadIdx.x] = b2[g * 2 + threadIdx.x];
  __syncthreads();
  // thread covers batches {bp, bp+16} x outputs {4*oq .. 4*oq+3}
  const int bp = threadIdx.x & 15, oq = threadIdx.x >> 4;
  const int o0 = 4 * oq;
  float acc[2][4];
#pragma unroll
  for (int i = 0; i < 2; i++)
#pragma unroll
    for (int j = 0; j < 4; j++) acc[i][j] = 0.f;
  for (int k4 = 0; k4 < 72; k4++) {
    const float4 f0 = *(const float4*)&sf[bp * 300 + 4 * k4];
    const float4 f1 = *(const float4*)&sf[(bp + 16) * 300 + 4 * k4];
#pragma unroll
    for (int j = 0; j < 4; j++) {
      const float4 wr = *(const float4*)&sw1[(o0 + j) * 292 + 4 * k4];
      acc[0][j] = fmaf(f0.x, wr.x, fmaf(f0.y, wr.y, fmaf(f0.z, wr.z, fmaf(f0.w, wr.w, acc[0][j]))));
      acc[1][j] = fmaf(f1.x, wr.x, fmaf(f1.y, wr.y, fmaf(f1.z, wr.z, fmaf(f1.w, wr.w, acc[1][j]))));
    }
  }
#pragma unroll
  for (int j = 0; j < 4; j++) {
    so[bp * 65 + o0 + j] = acc[0][j];
    so[(bp + 16) * 65 + o0 + j] = acc[1][j];
  }
  __syncthreads();
  if (threadIdx.x < 64) {
    const int bb = threadIdx.x >> 1, j = threadIdx.x & 1;
    float a = sb2[j];
#pragma unroll 8
    for (int o = 0; o < 64; o++) a = fmaf(so[bb * 65 + o], sw2[j * 64 + o], a);
    out[(b0 + bb) * 144 + g * 2 + j] = a;
  }
}

extern "C" void kernel_launch(void* const* d_in, const int* in_sizes, int n_in,
                              void* d_out, int out_size, void* d_ws, size_t ws_size,
                              hipStream_t stream) {
  const float* x   = (const float*)d_in[0];
  const float* w1  = (const float*)d_in[1];
  const float* b1  = (const float*)d_in[2];
  const float* w2  = (const float*)d_in[3];
  const float* b2  = (const float*)d_in[4];
  const float* w3  = (const float*)d_in[5];
  const float* b3  = (const float*)d_in[6];
  const float* l1w = (const float*)d_in[7];
  const float* l2w = (const float*)d_in[8];
  const float* l2b = (const float*)d_in[9];
  float* out = (float*)d_out;

  float* h1 = (float*)d_ws;          // 64*576*21*21  = 16,257,024 floats
  float* h2 = h1 + 16257024;         // 64*1152*9*9   =  5,971,968 floats
  float* h3 = h2 + 5971968;          // 64*2304*3*3   =  1,327,104 floats

  conv1_k<<<dim3(64 * NG), 256, 0, stream>>>(x,  w1, b1, h1);
  conv2_k<<<dim3(22 * NG), 256, 0, stream>>>(h1, w2, b2, h2);
  conv3_k<<<dim3(10 * NG), 256, 0, stream>>>(h2, w3, b3, h3);
  lin_k  <<<dim3(2 * NG),  256, 0, stream>>>(h3, l1w, l2w, l2b, out);
}